// Round 14
// baseline (285.117 us; speedup 1.0000x reference)
//
#include <hip/hip_runtime.h>
#include <hip/hip_bf16.h>
#include <stdint.h>

#define T_SEQ 336
#define NKT   11        // K-tiles of 32 (336 -> 352; tail zeroed in LDS, apack zero-padded)
#define P_LEN 720
#define NM16  48        // 16-row p-blocks in apack (768 rows, zero-padded)
#define C_LEN 1782
#define NB    64
#define CTILE 64        // cols per block: 64 floats = 2 x 128B lines (line-aligned tiles)
#define NCT   28        // 28*64 = 1792 >= 1782; last tile masked
#define NFR   4         // 16-col fragments per tile
#define BPITCH 360      // LDS row pitch (bf16); 64*720B = 46080 B -> 3 blocks/CU

typedef __attribute__((ext_vector_type(4))) float f32x4;
typedef __attribute__((ext_vector_type(8))) short s16x8;

__device__ __forceinline__ unsigned short f2bf(float f) {
  unsigned int u = __builtin_bit_cast(unsigned int, f);
  u += 0x7FFFu + ((u >> 16) & 1u);   // RNE
  return (unsigned short)(u >> 16);
}

// Weff[p,k] = Ws[p,k] + 0.2*sum_{t in win(k)} (Wt-Ws)[p,t], packed in MFMA
// fragment order: block m16*NKT+kt holds 64 lanes x 16B; lane lg*16+l16
// carries W[m16*16+l16][kt*32+lg*8+j], j=0..7. Zero-padded p>=720, k>=336.
__global__ __launch_bounds__(64) void prep_w(
    const float* __restrict__ Ws, const float* __restrict__ bs,
    const float* __restrict__ Wt, const float* __restrict__ bt,
    unsigned short* __restrict__ apack, float* __restrict__ bias) {
  const int p   = blockIdx.x;          // 0..767
  const int tid = threadIdx.x;         // 0..63
  if (tid < NKT * 4) {
    const int kt = tid >> 2;
    const int lg = tid & 3;
    const float* wsr = Ws + (size_t)p * T_SEQ;
    const float* wtr = Wt + (size_t)p * T_SEQ;
    union { s16x8 v; unsigned short u[8]; } pk;
#pragma unroll
    for (int j = 0; j < 8; ++j) {
      const int k = kt * 32 + lg * 8 + j;
      float val = 0.f;
      if (p < P_LEN && k < T_SEQ) {
        float d;
        if (k == 0) {
          d = 3.f*(wtr[0]-wsr[0]) + 2.f*(wtr[1]-wsr[1]) + (wtr[2]-wsr[2]);
        } else if (k == T_SEQ-1) {
          d = 3.f*(wtr[T_SEQ-1]-wsr[T_SEQ-1]) + 2.f*(wtr[T_SEQ-2]-wsr[T_SEQ-2])
              + (wtr[T_SEQ-3]-wsr[T_SEQ-3]);
        } else {
          int lo = (k-2 < 0) ? 0 : k-2;
          int hi = (k+2 > T_SEQ-1) ? T_SEQ-1 : k+2;
          d = 0.f;
          for (int t = lo; t <= hi; ++t) d += wtr[t]-wsr[t];
        }
        val = wsr[k] + 0.2f*d;
      }
      pk.u[j] = f2bf(val);
    }
    const int m16 = p >> 4;
    const int l16 = p & 15;
    *(s16x8*)&apack[(size_t)(((m16*NKT + kt) * 64) + lg*16 + l16) * 8] = pk.v;
  }
  if (tid == 0 && p < P_LEN) bias[p] = bs[p] + bt[p];
}

// O[b,p,c] = relu( sum_k Weff[p,k] * X[b,k,c] + bias[p] )
// Block = (batch, 64-col line-aligned slice) x ALL 768 p-rows; x staged to
// LDS once (one barrier), then 3 m-pairs x 11 kt with operand-swapped MFMA
// (D[c][p]: lane holds 4 consecutive c -> dwordx4 stores). R14 vs R13:
// CTILE 96->64 gives 3 resident blocks/CU (24 waves/CU, +50% TLP);
// non-temporal stores keep the 335MB write stream out of L2; setprio(1)
// around the MFMA cluster (independent waves, attn-like regime).
__global__ __launch_bounds__(512, 6) void gemm_kernel(
    const float* __restrict__ x, const unsigned short* __restrict__ apack,
    const float* __restrict__ bias, float* __restrict__ out) {
  __shared__ __align__(16) unsigned short Bp[CTILE * BPITCH];   // 46080 B

  // 1792 = 8 XCD x 224; XCD x hosts b in [x*8, x*8+8): same-b blocks share L2
  const int bid = blockIdx.x;
  const int swz = (bid & 7) * 224 + (bid >> 3);
  const int b   = swz / NCT;
  const int ct  = swz % NCT;
  const int c0  = ct * CTILE;

  const int tid  = threadIdx.x;
  const int lane = tid & 63;
  const int wid  = tid >> 6;      // 0..7
  const int l16  = lane & 15;
  const int lg   = lane >> 4;

  const float* xb = x + (size_t)b * T_SEQ * C_LEN;
  const s16x8* ap = (const s16x8*)apack;

  // ---- stage x panel: fp32 -> bf16, transposed to [c][k], pitch 360 ----
  // unit (cp 0..31, kg 0..41): cols c0+2cp..+1, k rows kg*8..+7
  for (int i = tid; i < 42 * 32; i += 512) {
    const int cp = i & 31;
    const int kg = i >> 5;
    int c = c0 + cp * 2; if (c > C_LEN - 2) c = C_LEN - 2;  // dup masked at store
    float2 v[8];
#pragma unroll
    for (int j = 0; j < 8; ++j)
      v[j] = *(const float2*)(xb + (size_t)(kg * 8 + j) * C_LEN + c);
    union { s16x8 vv; uint32_t dw[4]; } pa, pb;
#pragma unroll
    for (int h = 0; h < 4; ++h) {
      uint32_t ra, rb;
      asm("v_cvt_pk_bf16_f32 %0, %1, %2" : "=v"(ra) : "v"(v[2*h].x), "v"(v[2*h+1].x));
      asm("v_cvt_pk_bf16_f32 %0, %1, %2" : "=v"(rb) : "v"(v[2*h].y), "v"(v[2*h+1].y));
      pa.dw[h] = ra; pb.dw[h] = rb;
    }
    *(s16x8*)&Bp[(cp * 2)     * BPITCH + kg * 8] = pa.vv;
    *(s16x8*)&Bp[(cp * 2 + 1) * BPITCH + kg * 8] = pb.vv;
  }
  // zero k-tail 336..359 (kt=10 reads k up to 351)
  {
    const s16x8 z = {};
    for (int i = tid; i < CTILE * 3; i += 512)
      *(s16x8*)&Bp[(i / 3) * BPITCH + T_SEQ + (i % 3) * 8] = z;
  }
  __syncthreads();   // the only barrier

  const size_t ob = (size_t)b * P_LEN * C_LEN;

#pragma unroll 1
  for (int mp = 0; mp < 3; ++mp) {
    const int m16a = mp * 16 + wid * 2;     // covers 0..47 over (mp, wid, m)

    f32x4 acc[2][NFR] = {};
    s16x8 afc0 = ap[(size_t)((m16a)     * NKT) * 64 + lane];
    s16x8 afc1 = ap[(size_t)((m16a + 1) * NKT) * 64 + lane];

#pragma unroll
    for (int kt = 0; kt < NKT; ++kt) {
      s16x8 afn0, afn1;
      if (kt + 1 < NKT) {
        afn0 = ap[(size_t)((m16a)     * NKT + kt + 1) * 64 + lane];
        afn1 = ap[(size_t)((m16a + 1) * NKT + kt + 1) * 64 + lane];
      }
      s16x8 bf[NFR];
#pragma unroll
      for (int n = 0; n < NFR; ++n)
        bf[n] = *(const s16x8*)&Bp[(n * 16 + l16) * BPITCH + kt * 32 + lg * 8];
      __builtin_amdgcn_sched_barrier(0);
      // operand-swapped: D[c][p] (col=l16 -> p, row=lg*4+r -> c)
      __builtin_amdgcn_s_setprio(1);
#pragma unroll
      for (int n = 0; n < NFR; ++n) {
        acc[0][n] = __builtin_amdgcn_mfma_f32_16x16x32_bf16(
            bf[n], afc0, acc[0][n], 0, 0, 0);
        acc[1][n] = __builtin_amdgcn_mfma_f32_16x16x32_bf16(
            bf[n], afc1, acc[1][n], 0, 0, 0);
      }
      __builtin_amdgcn_s_setprio(0);
      if (kt + 1 < NKT) { afc0 = afn0; afc1 = afn1; }
    }

    // epilogue: bias + relu + non-temporal dwordx4 stores (lane = 4 consec c)
#pragma unroll
    for (int m = 0; m < 2; ++m) {
      const int m16 = m16a + m;
      if (m16 < 45) {                         // p < 720, uniform per fragment
        const float bvm = bias[m16 * 16 + l16];
        float* rowp = out + ob + (size_t)(m16 * 16 + l16) * C_LEN;
#pragma unroll
        for (int n = 0; n < NFR; ++n) {
          const int cb = c0 + n * 16 + lg * 4;
          f32x4 v;
#pragma unroll
          for (int r = 0; r < 4; ++r) v[r] = fmaxf(acc[m][n][r] + bvm, 0.f);
          if (cb + 3 < C_LEN) {
            __builtin_nontemporal_store(v, (f32x4*)(rowp + cb));
          } else {
#pragma unroll
            for (int r = 0; r < 4; ++r)
              if (cb + r < C_LEN)
                __builtin_nontemporal_store(v[r], rowp + cb + r);
          }
        }
      }
    }
  }
}

extern "C" void kernel_launch(void* const* d_in, const int* in_sizes, int n_in,
                              void* d_out, int out_size, void* d_ws, size_t ws_size,
                              hipStream_t stream) {
  (void)in_sizes; (void)n_in; (void)out_size; (void)ws_size;
  const float* x  = (const float*)d_in[0];
  const float* Ws = (const float*)d_in[1];
  const float* bs = (const float*)d_in[2];
  const float* Wt = (const float*)d_in[3];
  const float* bt = (const float*)d_in[4];
  float* out = (float*)d_out;

  // ws: Apack (48*11 blocks * 1KB = 540672 B) then bias (720 f32)
  unsigned short* apack = (unsigned short*)d_ws;
  float* biasp = (float*)((char*)d_ws + (size_t)NM16 * NKT * 1024);

  prep_w<<<dim3(768), dim3(64), 0, stream>>>(Ws, bs, Wt, bt, apack, biasp);
  gemm_kernel<<<dim3(NB * NCT), dim3(512), 0, stream>>>(x, apack, biasp, out);
}

// Round 15
// 166.859 us; speedup vs baseline: 1.7087x; 1.7087x over previous
//
#include <hip/hip_runtime.h>
#include <hip/hip_bf16.h>
#include <stdint.h>

#define T_SEQ 336
#define NKT   11        // K-tiles of 32 (336 -> 352; tail zeroed in LDS, apack zero-padded)
#define P_LEN 720
#define NM16  48        // 16-row p-blocks in apack (768 rows, zero-padded)
#define C_LEN 1782
#define NB    64
#define CTILE 96        // cols per block: 96 floats = 3 x 128B lines (line-aligned tiles)
#define NCT   19        // ceil(1782/96); last tile masked
#define NFR   6         // 16-col fragments per tile
#define BPITCH 360      // LDS row pitch (bf16); 96*720B = 69120 B -> 2 blocks/CU

typedef __attribute__((ext_vector_type(4))) float f32x4;
typedef __attribute__((ext_vector_type(8))) short s16x8;

__device__ __forceinline__ unsigned short f2bf(float f) {
  unsigned int u = __builtin_bit_cast(unsigned int, f);
  u += 0x7FFFu + ((u >> 16) & 1u);   // RNE
  return (unsigned short)(u >> 16);
}

// Weff[p,k] = Ws[p,k] + 0.2*sum_{t in win(k)} (Wt-Ws)[p,t], packed in MFMA
// fragment order: block m16*NKT+kt holds 64 lanes x 16B; lane lg*16+l16
// carries W[m16*16+l16][kt*32+lg*8+j], j=0..7. Zero-padded p>=720, k>=336.
__global__ __launch_bounds__(64) void prep_w(
    const float* __restrict__ Ws, const float* __restrict__ bs,
    const float* __restrict__ Wt, const float* __restrict__ bt,
    unsigned short* __restrict__ apack, float* __restrict__ bias) {
  const int p   = blockIdx.x;          // 0..767
  const int tid = threadIdx.x;         // 0..63
  if (tid < NKT * 4) {
    const int kt = tid >> 2;
    const int lg = tid & 3;
    const float* wsr = Ws + (size_t)p * T_SEQ;
    const float* wtr = Wt + (size_t)p * T_SEQ;
    union { s16x8 v; unsigned short u[8]; } pk;
#pragma unroll
    for (int j = 0; j < 8; ++j) {
      const int k = kt * 32 + lg * 8 + j;
      float val = 0.f;
      if (p < P_LEN && k < T_SEQ) {
        float d;
        if (k == 0) {
          d = 3.f*(wtr[0]-wsr[0]) + 2.f*(wtr[1]-wsr[1]) + (wtr[2]-wsr[2]);
        } else if (k == T_SEQ-1) {
          d = 3.f*(wtr[T_SEQ-1]-wsr[T_SEQ-1]) + 2.f*(wtr[T_SEQ-2]-wsr[T_SEQ-2])
              + (wtr[T_SEQ-3]-wsr[T_SEQ-3]);
        } else {
          int lo = (k-2 < 0) ? 0 : k-2;
          int hi = (k+2 > T_SEQ-1) ? T_SEQ-1 : k+2;
          d = 0.f;
          for (int t = lo; t <= hi; ++t) d += wtr[t]-wsr[t];
        }
        val = wsr[k] + 0.2f*d;
      }
      pk.u[j] = f2bf(val);
    }
    const int m16 = p >> 4;
    const int l16 = p & 15;
    *(s16x8*)&apack[(size_t)(((m16*NKT + kt) * 64) + lg*16 + l16) * 8] = pk.v;
  }
  if (tid == 0 && p < P_LEN) bias[p] = bs[p] + bt[p];
}

// O[b,p,c] = relu( sum_k Weff[p,k] * X[b,k,c] + bias[p] )
// Block = (batch, 96-col line-aligned slice) x ALL 768 p-rows; x staged to
// LDS once (one barrier); operand-swapped MFMA (D[c][p]: lane holds 4
// consecutive c -> dwordx4 stores). R15 vs R13: 2 passes x 3 m16-frags/wave
// (was 3 passes x 2) -- per-block LDS B-read traffic 1584->1056 KB, MFMA
// burst 12->18 per kt, VGPR ~120 (still 4 waves/SIMD, 2 blocks/CU).
__global__ __launch_bounds__(512, 4) void gemm_kernel(
    const float* __restrict__ x, const unsigned short* __restrict__ apack,
    const float* __restrict__ bias, float* __restrict__ out) {
  __shared__ __align__(16) unsigned short Bp[CTILE * BPITCH];   // 69120 B

  // 1216 = 8 XCD x 152; XCD x hosts b in [x*8, x*8+8): same-b blocks share L2
  const int bid = blockIdx.x;
  const int swz = (bid & 7) * 152 + (bid >> 3);
  const int b   = swz / NCT;
  const int ct  = swz % NCT;
  const int c0  = ct * CTILE;

  const int tid  = threadIdx.x;
  const int lane = tid & 63;
  const int wid  = tid >> 6;      // 0..7
  const int l16  = lane & 15;
  const int lg   = lane >> 4;

  const float* xb = x + (size_t)b * T_SEQ * C_LEN;
  const s16x8* ap = (const s16x8*)apack;

  // ---- stage x panel: fp32 -> bf16, transposed to [c][k], pitch 360 ----
  for (int i = tid; i < 42 * 48; i += 512) {
    const int cp = i % 48;
    const int kg = i / 48;
    int c = c0 + cp * 2; if (c > C_LEN - 2) c = C_LEN - 2;  // dup masked at store
    float2 v[8];
#pragma unroll
    for (int j = 0; j < 8; ++j)
      v[j] = *(const float2*)(xb + (size_t)(kg * 8 + j) * C_LEN + c);
    union { s16x8 vv; uint32_t dw[4]; } pa, pb;
#pragma unroll
    for (int h = 0; h < 4; ++h) {
      uint32_t ra, rb;
      asm("v_cvt_pk_bf16_f32 %0, %1, %2" : "=v"(ra) : "v"(v[2*h].x), "v"(v[2*h+1].x));
      asm("v_cvt_pk_bf16_f32 %0, %1, %2" : "=v"(rb) : "v"(v[2*h].y), "v"(v[2*h+1].y));
      pa.dw[h] = ra; pb.dw[h] = rb;
    }
    *(s16x8*)&Bp[(cp * 2)     * BPITCH + kg * 8] = pa.vv;
    *(s16x8*)&Bp[(cp * 2 + 1) * BPITCH + kg * 8] = pb.vv;
  }
  // zero k-tail 336..359 (kt=10 reads k up to 351)
  {
    const s16x8 z = {};
    for (int i = tid; i < CTILE * 3; i += 512)
      *(s16x8*)&Bp[(i / 3) * BPITCH + T_SEQ + (i % 3) * 8] = z;
  }
  __syncthreads();   // the only barrier

  const size_t ob = (size_t)b * P_LEN * C_LEN;

#pragma unroll 1
  for (int pass = 0; pass < 2; ++pass) {
    const int m16a = pass * 24 + wid * 3;   // 3 m16-frags per wave per pass

    f32x4 acc[3][NFR] = {};

#pragma unroll
    for (int kt = 0; kt < NKT; ++kt) {
      s16x8 af[3];
#pragma unroll
      for (int m = 0; m < 3; ++m)
        af[m] = ap[(size_t)((m16a + m) * NKT + kt) * 64 + lane];
      s16x8 bf[NFR];
#pragma unroll
      for (int n = 0; n < NFR; ++n)
        bf[n] = *(const s16x8*)&Bp[(n * 16 + l16) * BPITCH + kt * 32 + lg * 8];
      __builtin_amdgcn_sched_barrier(0);
      // operand-swapped: D[c][p] (col=l16 -> p, row=lg*4+r -> c)
#pragma unroll
      for (int m = 0; m < 3; ++m)
#pragma unroll
        for (int n = 0; n < NFR; ++n)
          acc[m][n] = __builtin_amdgcn_mfma_f32_16x16x32_bf16(
              bf[n], af[m], acc[m][n], 0, 0, 0);
    }

    // epilogue: bias + relu + dwordx4 stores (lane = 4 consecutive c)
#pragma unroll
    for (int m = 0; m < 3; ++m) {
      const int m16 = m16a + m;
      if (m16 < 45) {                         // p < 720, uniform per fragment
        const float bvm = bias[m16 * 16 + l16];
        float* rowp = out + ob + (size_t)(m16 * 16 + l16) * C_LEN;
#pragma unroll
        for (int n = 0; n < NFR; ++n) {
          const int cb = c0 + n * 16 + lg * 4;
          f32x4 v;
#pragma unroll
          for (int r = 0; r < 4; ++r) v[r] = fmaxf(acc[m][n][r] + bvm, 0.f);
          if (cb + 3 < C_LEN) {
            *(f32x4*)(rowp + cb) = v;
          } else {
#pragma unroll
            for (int r = 0; r < 4; ++r)
              if (cb + r < C_LEN) rowp[cb + r] = v[r];
          }
        }
      }
    }
  }
}

extern "C" void kernel_launch(void* const* d_in, const int* in_sizes, int n_in,
                              void* d_out, int out_size, void* d_ws, size_t ws_size,
                              hipStream_t stream) {
  (void)in_sizes; (void)n_in; (void)out_size; (void)ws_size;
  const float* x  = (const float*)d_in[0];
  const float* Ws = (const float*)d_in[1];
  const float* bs = (const float*)d_in[2];
  const float* Wt = (const float*)d_in[3];
  const float* bt = (const float*)d_in[4];
  float* out = (float*)d_out;

  // ws: Apack (48*11 blocks * 1KB = 540672 B) then bias (720 f32)
  unsigned short* apack = (unsigned short*)d_ws;
  float* biasp = (float*)((char*)d_ws + (size_t)NM16 * NKT * 1024);

  prep_w<<<dim3(768), dim3(64), 0, stream>>>(Ws, bs, Wt, bt, apack, biasp);
  gemm_kernel<<<dim3(NB * NCT), dim3(512), 0, stream>>>(x, apack, biasp, out);
}